// Round 1
// baseline (982.393 us; speedup 1.0000x reference)
//
#include <hip/hip_runtime.h>
#include <hip/hip_bf16.h>
#include <type_traits>

// MHA forward: B=4,S=2048,D=1024,H=16,DK=DV=64, causal.
// Pipeline: Q/K/V proj GEMMs (fp32->bf16) -> flash attention (bf16 MFMA) -> out proj.

typedef __attribute__((ext_vector_type(8))) __bf16 bf16x8;
typedef __attribute__((ext_vector_type(8))) unsigned short ushort8v;
typedef __attribute__((ext_vector_type(4))) unsigned short ushort4v;
typedef __attribute__((ext_vector_type(4))) float float4v;

#define MFMA16(a, b, c) __builtin_amdgcn_mfma_f32_16x16x32_bf16((a), (b), (c), 0, 0, 0)

__device__ __forceinline__ unsigned short f2bf(float f) {
    union { float f; unsigned u; } v; v.f = f;
    unsigned r = v.u + 0x7fffu + ((v.u >> 16) & 1u);   // RNE
    return (unsigned short)(r >> 16);
}

// ---------------------------------------------------------------------------
// GEMM: C[M,N] = A[M,K] @ B[K,N].  A: fp32 or bf16(u16) row-major; B fp32
// row-major; C fp32 or bf16.  128x128 tile, BK=64, 4 waves of 64x64 each.
// LDS stride 72 (144B = 9*16B): 16B-aligned rows, banks spread by 4.
// ---------------------------------------------------------------------------
template <typename AT, typename OT>
__global__ __launch_bounds__(256) void gemm_bf16_k(
    const AT* __restrict__ A, const float* __restrict__ Bw, OT* __restrict__ C,
    int M, int N, int K)
{
    __shared__ unsigned short As[128 * 72];
    __shared__ unsigned short Bs[128 * 72];

    const int t = threadIdx.x;
    const int lane = t & 63, w = t >> 6;
    const int lanelo = lane & 15, quad = lane >> 4;
    const int wm = w >> 1, wn = w & 1;
    const int m0 = blockIdx.y * 128, n0 = blockIdx.x * 128;

    float4v acc[4][4];
    for (int i = 0; i < 4; i++)
        for (int j = 0; j < 4; j++) acc[i][j] = (float4v)(0.f);

    for (int k0 = 0; k0 < K; k0 += 64) {
        // ---- stage A tile (128 x 64) ----
        for (int i = 0; i < 8; i++) {
            int c = i * 256 + t;
            int row = c >> 4, col = (c & 15) * 4;
            ushort4v o4;
            if constexpr (std::is_same<AT, float>::value) {
                float4v av = *(const float4v*)&A[(size_t)(m0 + row) * K + k0 + col];
                o4.x = f2bf(av.x); o4.y = f2bf(av.y);
                o4.z = f2bf(av.z); o4.w = f2bf(av.w);
            } else {
                o4 = *(const ushort4v*)&A[(size_t)(m0 + row) * K + k0 + col];
            }
            *(ushort4v*)&As[row * 72 + col] = o4;
        }
        // ---- stage B tile (64 x 128), transposed to Bs[n][k] ----
        for (int i = 0; i < 8; i++) {
            int c = i * 256 + t;
            int krow = c >> 5, n = (c & 31) * 4;
            float4v bv = *(const float4v*)&Bw[(size_t)(k0 + krow) * N + n0 + n];
            Bs[(n + 0) * 72 + krow] = f2bf(bv.x);
            Bs[(n + 1) * 72 + krow] = f2bf(bv.y);
            Bs[(n + 2) * 72 + krow] = f2bf(bv.z);
            Bs[(n + 3) * 72 + krow] = f2bf(bv.w);
        }
        __syncthreads();

        for (int ks = 0; ks < 2; ks++) {
            bf16x8 af[4], bfr[4];
            for (int mi = 0; mi < 4; mi++)
                af[mi] = *(const bf16x8*)&As[(wm * 64 + mi * 16 + lanelo) * 72 + ks * 32 + quad * 8];
            for (int ni = 0; ni < 4; ni++)
                bfr[ni] = *(const bf16x8*)&Bs[(wn * 64 + ni * 16 + lanelo) * 72 + ks * 32 + quad * 8];
            for (int mi = 0; mi < 4; mi++)
                for (int ni = 0; ni < 4; ni++)
                    acc[mi][ni] = MFMA16(af[mi], bfr[ni], acc[mi][ni]);
        }
        __syncthreads();
    }

    // epilogue: C layout col=lane&15, row=quad*4+reg
    for (int mi = 0; mi < 4; mi++)
        for (int ni = 0; ni < 4; ni++) {
            int col = n0 + wn * 64 + ni * 16 + lanelo;
            for (int r = 0; r < 4; r++) {
                int row = m0 + wm * 64 + mi * 16 + quad * 4 + r;
                float v = acc[mi][ni][r];
                if constexpr (std::is_same<OT, float>::value)
                    C[(size_t)row * N + col] = v;
                else
                    C[(size_t)row * N + col] = f2bf(v);
            }
        }
}

// ---------------------------------------------------------------------------
// Flash-style causal attention.  One block = 64 Q-rows of one (b,h).
// 4 waves x 16 Q-rows.  K/V tiles (64 keys) staged in LDS; V transposed.
// Online softmax with per-row (m,l) in registers (replicated over the quad's
// 16 lanes).  P goes C-layout -> LDS -> A-layout for the PV MFMA.
// ---------------------------------------------------------------------------
__global__ __launch_bounds__(256) void attn_k(
    const unsigned short* __restrict__ Qb, const unsigned short* __restrict__ Kb,
    const unsigned short* __restrict__ Vb, unsigned short* __restrict__ Ob)
{
    __shared__ unsigned short Ks[64 * 72];
    __shared__ unsigned short Vt[64 * 72];
    __shared__ unsigned short Ps[4][16 * 72];

    const int t = threadIdx.x;
    const int lane = t & 63, w = t >> 6;
    const int lanelo = lane & 15, quad = lane >> 4;
    const int qb = blockIdx.x * 64;
    const int bh = blockIdx.y;            // b*16 + h
    const int b = bh >> 4, h = bh & 15;
    const size_t base = ((size_t)b * 2048) * 1024 + (size_t)h * 64;

    // Q fragments for this wave's 16 rows (A-layout: m=lane&15, k=quad*8+j)
    bf16x8 qf[2];
    {
        int qrow = qb + w * 16 + lanelo;
        const unsigned short* qp = Qb + base + (size_t)qrow * 1024 + quad * 8;
        qf[0] = *(const bf16x8*)(qp);
        qf[1] = *(const bf16x8*)(qp + 32);
    }

    float4v o[4];
    for (int i = 0; i < 4; i++) o[i] = (float4v)(0.f);
    float mrow[4], lrow[4];
    for (int r = 0; r < 4; r++) { mrow[r] = -__builtin_inff(); lrow[r] = 0.f; }

    const int myrow_hi = qb + w * 16 + 15;
    const int nkt = blockIdx.x + 1;       // causal: tiles 0..qb/64

    for (int kt = 0; kt < nkt; kt++) {
        // ---- stage K tile and V^T tile ----
        for (int i = 0; i < 2; i++) {
            int c = i * 256 + t;
            int row = c >> 3, col = (c & 7) * 8;
            const unsigned short* gk = Kb + base + (size_t)(kt * 64 + row) * 1024 + col;
            *(ushort8v*)&Ks[row * 72 + col] = *(const ushort8v*)gk;
            const unsigned short* gv = Vb + base + (size_t)(kt * 64 + row) * 1024 + col;
            ushort8v vv = *(const ushort8v*)gv;
            for (int j = 0; j < 8; j++) Vt[(col + j) * 72 + row] = vv[j];
        }
        __syncthreads();

        if (kt * 64 <= myrow_hi) {        // wave-uniform causal skip
            // ---- scores: S = Q K^T, 4 tiles of 16 keys ----
            float4v sc[4];
            for (int nt = 0; nt < 4; nt++) {
                sc[nt] = (float4v)(0.f);
                for (int c = 0; c < 2; c++) {
                    bf16x8 kf = *(const bf16x8*)&Ks[(nt * 16 + lanelo) * 72 + c * 32 + quad * 8];
                    sc[nt] = MFMA16(qf[c], kf, sc[nt]);
                }
            }
            // ---- online softmax (C layout: col=lane&15, row=quad*4+r) ----
            const int rowbase = qb + w * 16 + quad * 4;
            const int colb = kt * 64 + lanelo;
            float p[4][4];
            for (int r = 0; r < 4; r++) {
                float mx = -__builtin_inff();
                for (int nt = 0; nt < 4; nt++) {
                    float s = sc[nt][r] * 0.125f;                 // 1/sqrt(64)
                    if (colb + nt * 16 > rowbase + r) s = -__builtin_inff();
                    p[nt][r] = s;
                    mx = fmaxf(mx, s);
                }
                for (int sh = 1; sh < 16; sh <<= 1) mx = fmaxf(mx, __shfl_xor(mx, sh, 64));
                float mnew = fmaxf(mrow[r], mx);
                float alpha = __expf(mrow[r] - mnew);
                float rs = 0.f;
                for (int nt = 0; nt < 4; nt++) {
                    float e = __expf(p[nt][r] - mnew);
                    p[nt][r] = e; rs += e;
                }
                for (int sh = 1; sh < 16; sh <<= 1) rs += __shfl_xor(rs, sh, 64);
                lrow[r] = lrow[r] * alpha + rs;
                mrow[r] = mnew;
                for (int vt = 0; vt < 4; vt++) o[vt][r] *= alpha;
            }
            // ---- P: C-layout -> LDS (per-wave region, no cross-wave dep) ----
            unsigned short* pw = &Ps[w][0];
            for (int r = 0; r < 4; r++)
                for (int nt = 0; nt < 4; nt++)
                    pw[(quad * 4 + r) * 72 + nt * 16 + lanelo] = f2bf(p[nt][r]);
            asm volatile("s_waitcnt lgkmcnt(0)" ::: "memory");
            // ---- O += P V ----
            for (int c = 0; c < 2; c++) {
                bf16x8 pf = *(const bf16x8*)&pw[lanelo * 72 + c * 32 + quad * 8];
                for (int vt = 0; vt < 4; vt++) {
                    bf16x8 vf = *(const bf16x8*)&Vt[(vt * 16 + lanelo) * 72 + c * 32 + quad * 8];
                    o[vt] = MFMA16(pf, vf, o[vt]);
                }
            }
        }
        __syncthreads();
    }

    // epilogue: normalize by l, store bf16 [B,S,H*DV]
    const int rowbase = qb + w * 16 + quad * 4;
    for (int vt = 0; vt < 4; vt++) {
        int col = h * 64 + vt * 16 + lanelo;
        for (int r = 0; r < 4; r++) {
            float v = o[vt][r] / lrow[r];
            Ob[((size_t)(b * 2048 + rowbase + r)) * 1024 + col] = f2bf(v);
        }
    }
}

// ---------------------------------------------------------------------------
extern "C" void kernel_launch(void* const* d_in, const int* in_sizes, int n_in,
                              void* d_out, int out_size, void* d_ws, size_t ws_size,
                              hipStream_t stream) {
    const float* queries = (const float*)d_in[0];
    const float* keys    = (const float*)d_in[1];
    const float* values  = (const float*)d_in[2];
    // d_in[3] = causal tril mask; implemented analytically in attn_k.
    const float* W_Q = (const float*)d_in[4];
    const float* W_K = (const float*)d_in[5];
    const float* W_V = (const float*)d_in[6];
    const float* W_O = (const float*)d_in[7];
    float* out = (float*)d_out;

    const size_t SZ = (size_t)4 * 2048 * 1024;    // 8,388,608 elems per buffer
    unsigned short* Qb = (unsigned short*)d_ws;   // bf16 buffers in ws (67 MB)
    unsigned short* Kb = Qb + SZ;
    unsigned short* Vb = Kb + SZ;
    unsigned short* Ab = Vb + SZ;

    dim3 gg(8, 64), blk(256);
    hipLaunchKernelGGL((gemm_bf16_k<float, unsigned short>), gg, blk, 0, stream,
                       queries, W_Q, Qb, 8192, 1024, 1024);
    hipLaunchKernelGGL((gemm_bf16_k<float, unsigned short>), gg, blk, 0, stream,
                       keys, W_K, Kb, 8192, 1024, 1024);
    hipLaunchKernelGGL((gemm_bf16_k<float, unsigned short>), gg, blk, 0, stream,
                       values, W_V, Vb, 8192, 1024, 1024);
    hipLaunchKernelGGL(attn_k, dim3(32, 64), blk, 0, stream, Qb, Kb, Vb, Ab);
    hipLaunchKernelGGL((gemm_bf16_k<unsigned short, float>), gg, blk, 0, stream,
                       Ab, W_O, out, 8192, 1024, 1024);
}

// Round 2
// 579.462 us; speedup vs baseline: 1.6954x; 1.6954x over previous
//
#include <hip/hip_runtime.h>
#include <hip/hip_bf16.h>

// MHA forward: B=4,S=2048,D=1024,H=16,DK=DV=64, causal.
// v2: weights pre-transposed to bf16 [N,K]; m97-style GEMMs with
// global_load_lds(16B); attention with swizzled (conflict-free) V^T and P
// LDS layouts, K staged via global_load_lds, heavy-qtile-first order.

typedef __attribute__((ext_vector_type(8))) __bf16 bf16x8;
typedef __attribute__((ext_vector_type(8))) unsigned short ushort8v;
typedef __attribute__((ext_vector_type(4))) unsigned short ushort4v;
typedef __attribute__((ext_vector_type(4))) unsigned uint4v;
typedef __attribute__((ext_vector_type(4))) float float4v;

#define MFMA16(a, b, c) __builtin_amdgcn_mfma_f32_16x16x32_bf16((a), (b), (c), 0, 0, 0)

// async global->LDS, 16B per lane
#define GLDS16(g, l)                                                     \
    __builtin_amdgcn_global_load_lds(                                    \
        (const __attribute__((address_space(1))) void*)(g),              \
        (__attribute__((address_space(3))) void*)(l), 16, 0, 0)

__device__ __forceinline__ unsigned short f2bf(float f) {   // RNE
    union { float f; unsigned u; } v; v.f = f;
    unsigned r = v.u + 0x7fffu + ((v.u >> 16) & 1u);
    return (unsigned short)(r >> 16);
}
// pack 2 floats -> 2 bf16 (round-half-up): bias + byte-perm, 3 VALU / 2 elems
__device__ __forceinline__ unsigned pkbf(float a, float b) {
    union { float f; unsigned u; } x, y; x.f = a; y.f = b;
    return __builtin_amdgcn_perm(y.u + 0x8000u, x.u + 0x8000u, 0x07060302u);
}

// ---------------------------------------------------------------------------
// W [K=1024][N=1024] fp32 -> Wt [N][K] bf16 (RNE)
// ---------------------------------------------------------------------------
__global__ __launch_bounds__(256) void transpose_w(
    const float* __restrict__ W, unsigned short* __restrict__ Wt)
{
    __shared__ unsigned short T[64][72];
    const int t = threadIdx.x;
    const int n0 = blockIdx.x * 64, k0 = blockIdx.y * 64;
    for (int i = 0; i < 4; i++) {
        int idx = i * 256 + t, r = idx >> 4, c = (idx & 15) * 4;   // k=r, n=c
        float4v v = *(const float4v*)&W[(size_t)(k0 + r) * 1024 + n0 + c];
        T[c + 0][r] = f2bf(v.x); T[c + 1][r] = f2bf(v.y);
        T[c + 2][r] = f2bf(v.z); T[c + 3][r] = f2bf(v.w);
    }
    __syncthreads();
    for (int i = 0; i < 4; i++) {
        int idx = i * 256 + t, r = idx >> 4, c = (idx & 15) * 4;   // n=r, k=c
        ushort4v o; o.x = T[r][c]; o.y = T[r][c + 1]; o.z = T[r][c + 2]; o.w = T[r][c + 3];
        *(ushort4v*)&Wt[(size_t)(n0 + r) * 1024 + k0 + c] = o;
    }
}

// ---------------------------------------------------------------------------
// GEMM: C[M,N] = A[M,K] @ Bt[N,K]^T.  A fp32 (converted in staging) or bf16
// (global_load_lds).  Bt bf16 via global_load_lds.  128x128 tile, BK=64.
// ---------------------------------------------------------------------------
template <bool A_F32, bool OUT_BF16>
__global__ __launch_bounds__(256) void gemm2(
    const void* __restrict__ Ap, const unsigned short* __restrict__ Bt,
    void* __restrict__ Cp, int M, int N, int K, float scale)
{
    constexpr int LDA = A_F32 ? 72 : 64;     // 72 shorts = 144B = 9*16B aligned
    __shared__ unsigned short As[128 * LDA];
    __shared__ unsigned short Bs[128 * 64];

    const int t = threadIdx.x;
    const int lane = t & 63, w = t >> 6;
    const int lanelo = lane & 15, quad = lane >> 4;
    const int wm = w >> 1, wn = w & 1;
    const int m0 = blockIdx.y * 128, n0 = blockIdx.x * 128;

    float4v acc[4][4];
    for (int i = 0; i < 4; i++)
        for (int j = 0; j < 4; j++) acc[i][j] = (float4v)(0.f);

    for (int k0 = 0; k0 < K; k0 += 64) {
        if constexpr (A_F32) {
            const float* A = (const float*)Ap;
            for (int i = 0; i < 4; i++) {
                int idx = i * 256 + t, row = idx >> 3, ch = idx & 7;
                const float* ga = A + (size_t)(m0 + row) * K + k0 + ch * 8;
                float4v a0 = *(const float4v*)ga;
                float4v a1 = *(const float4v*)(ga + 4);
                uint4v o = { pkbf(a0.x, a0.y), pkbf(a0.z, a0.w),
                             pkbf(a1.x, a1.y), pkbf(a1.z, a1.w) };
                *(uint4v*)&As[row * LDA + ch * 8] = o;
            }
        } else {
            const unsigned short* A = (const unsigned short*)Ap;
            for (int i = 0; i < 4; i++) {
                int idx = i * 256 + t, row = idx >> 3, ch = idx & 7;
                GLDS16(A + (size_t)(m0 + row) * K + k0 + ch * 8, &As[idx * 8]);
            }
        }
        for (int i = 0; i < 4; i++) {
            int idx = i * 256 + t, row = idx >> 3, ch = idx & 7;
            GLDS16(Bt + (size_t)(n0 + row) * K + k0 + ch * 8, &Bs[idx * 8]);
        }
        __syncthreads();

        for (int ks = 0; ks < 2; ks++) {
            bf16x8 af[4], bfr[4];
            for (int mi = 0; mi < 4; mi++)
                af[mi] = *(const bf16x8*)&As[(wm * 64 + mi * 16 + lanelo) * LDA + ks * 32 + quad * 8];
            for (int ni = 0; ni < 4; ni++)
                bfr[ni] = *(const bf16x8*)&Bs[(wn * 64 + ni * 16 + lanelo) * 64 + ks * 32 + quad * 8];
            for (int mi = 0; mi < 4; mi++)
                for (int ni = 0; ni < 4; ni++)
                    acc[mi][ni] = MFMA16(af[mi], bfr[ni], acc[mi][ni]);
        }
        __syncthreads();
    }

    for (int mi = 0; mi < 4; mi++)
        for (int ni = 0; ni < 4; ni++) {
            int col = n0 + wn * 64 + ni * 16 + lanelo;
            for (int r = 0; r < 4; r++) {
                int row = m0 + wm * 64 + mi * 16 + quad * 4 + r;
                float v = acc[mi][ni][r] * scale;
                if constexpr (OUT_BF16)
                    ((unsigned short*)Cp)[(size_t)row * N + col] = f2bf(v);
                else
                    ((float*)Cp)[(size_t)row * N + col] = v;
            }
        }
}

// ---------------------------------------------------------------------------
// Flash causal attention.  Block = 64 Q-rows of one (b,h), heavy-first order.
// Q pre-scaled by 1/8.  Ks via global_load_lds; Vt swizzled (key ^ 8*(dv>>3));
// P per-wave, swizzled (col ^ 16*quad).  All LDS accesses conflict-free or
// m97-pattern.
// ---------------------------------------------------------------------------
__global__ __launch_bounds__(256) void attn_k(
    const unsigned short* __restrict__ Qb, const unsigned short* __restrict__ Kb,
    const unsigned short* __restrict__ Vb, unsigned short* __restrict__ Ob)
{
    __shared__ unsigned short Ks[64 * 64];
    __shared__ unsigned short Vt[64 * 64];
    __shared__ unsigned short Ps[4][16 * 64];

    const int t = threadIdx.x;
    const int lane = t & 63, w = t >> 6;
    const int lanelo = lane & 15, quad = lane >> 4;
    const int qt = gridDim.x - 1 - blockIdx.x;       // heavy blocks first
    const int qb = qt * 64;
    const int bh = blockIdx.y;
    const int b = bh >> 4, h = bh & 15;
    const size_t base = ((size_t)b * 2048) * 1024 + (size_t)h * 64;

    bf16x8 qf[2];
    {
        int qrow = qb + w * 16 + lanelo;
        const unsigned short* qp = Qb + base + (size_t)qrow * 1024 + quad * 8;
        qf[0] = *(const bf16x8*)(qp);
        qf[1] = *(const bf16x8*)(qp + 32);
    }

    float4v o[4];
    for (int i = 0; i < 4; i++) o[i] = (float4v)(0.f);
    float mrow[4], lrow[4];
    for (int r = 0; r < 4; r++) { mrow[r] = -__builtin_inff(); lrow[r] = 0.f; }

    const int myrow_hi = qb + w * 16 + 15;
    const int nkt = qt + 1;

    for (int kt = 0; kt < nkt; kt++) {
        // K tile: 64x64 bf16 via global_load_lds
        for (int i = 0; i < 2; i++) {
            int idx = i * 256 + t, row = idx >> 3, ch = idx & 7;
            GLDS16(Kb + base + (size_t)(kt * 64 + row) * 1024 + ch * 8, &Ks[idx * 8]);
        }
        // V tile transposed with XOR swizzle: (dv,key) at Vt[dv*64 + (key ^ 8*(dv>>3))]
        for (int i = 0; i < 2; i++) {
            int c = i * 256 + t;
            int row = c >> 3, col = (c & 7) * 8;     // key, dv-base
            ushort8v vv = *(const ushort8v*)(Vb + base + (size_t)(kt * 64 + row) * 1024 + col);
            int krow = row ^ ((c & 7) * 8);
            for (int j = 0; j < 8; j++) Vt[(col + j) * 64 + krow] = vv[j];
        }
        __syncthreads();

        if (kt * 64 <= myrow_hi) {
            float4v sc[4];
            for (int nt = 0; nt < 4; nt++) {
                sc[nt] = (float4v)(0.f);
                for (int c = 0; c < 2; c++) {
                    bf16x8 kf = *(const bf16x8*)&Ks[(nt * 16 + lanelo) * 64 + c * 32 + quad * 8];
                    sc[nt] = MFMA16(qf[c], kf, sc[nt]);
                }
            }
            const int rowbase = qb + w * 16 + quad * 4;
            const int colb = kt * 64 + lanelo;
            float p[4][4];
            for (int r = 0; r < 4; r++) {
                float mx = -__builtin_inff();
                for (int nt = 0; nt < 4; nt++) {
                    float s = sc[nt][r];                        // Q pre-scaled
                    if (colb + nt * 16 > rowbase + r) s = -__builtin_inff();
                    p[nt][r] = s;
                    mx = fmaxf(mx, s);
                }
                for (int sh = 1; sh < 16; sh <<= 1) mx = fmaxf(mx, __shfl_xor(mx, sh, 64));
                float mnew = fmaxf(mrow[r], mx);
                float alpha = __expf(mrow[r] - mnew);
                float rs = 0.f;
                for (int nt = 0; nt < 4; nt++) {
                    float e = __expf(p[nt][r] - mnew);
                    p[nt][r] = e; rs += e;
                }
                for (int sh = 1; sh < 16; sh <<= 1) rs += __shfl_xor(rs, sh, 64);
                lrow[r] = lrow[r] * alpha + rs;
                mrow[r] = mnew;
                for (int vt = 0; vt < 4; vt++) o[vt][r] *= alpha;
            }
            // P: C-layout -> per-wave LDS, swizzled col^(16*quad): conflict-free
            unsigned short* pw = &Ps[w][0];
            for (int r = 0; r < 4; r++)
                for (int nt = 0; nt < 4; nt++)
                    pw[(quad * 4 + r) * 64 + ((nt * 16 + lanelo) ^ (quad * 16))] = f2bf(p[nt][r]);
            asm volatile("s_waitcnt lgkmcnt(0)" ::: "memory");
            for (int c = 0; c < 2; c++) {
                bf16x8 pf = *(const bf16x8*)&pw[lanelo * 64 + ((c * 32 + quad * 8) ^ ((lanelo >> 2) * 16))];
                for (int vt = 0; vt < 4; vt++) {
                    bf16x8 vf = *(const bf16x8*)&Vt[(vt * 16 + lanelo) * 64 +
                                                    ((c * 32 + quad * 8) ^ (((vt * 16 + lanelo) >> 3) * 8))];
                    o[vt] = MFMA16(pf, vf, o[vt]);
                }
            }
        }
        __syncthreads();
    }

    const int rowbase = qb + w * 16 + quad * 4;
    for (int vt = 0; vt < 4; vt++) {
        int col = h * 64 + vt * 16 + lanelo;
        for (int r = 0; r < 4; r++) {
            float v = o[vt][r] / lrow[r];
            Ob[((size_t)(b * 2048 + rowbase + r)) * 1024 + col] = f2bf(v);
        }
    }
}

// ---------------------------------------------------------------------------
extern "C" void kernel_launch(void* const* d_in, const int* in_sizes, int n_in,
                              void* d_out, int out_size, void* d_ws, size_t ws_size,
                              hipStream_t stream) {
    const float* queries = (const float*)d_in[0];
    const float* keys    = (const float*)d_in[1];
    const float* values  = (const float*)d_in[2];
    // d_in[3] = causal mask, handled analytically
    const float* W_Q = (const float*)d_in[4];
    const float* W_K = (const float*)d_in[5];
    const float* W_V = (const float*)d_in[6];
    const float* W_O = (const float*)d_in[7];

    const size_t SZ = (size_t)4 * 2048 * 1024;        // activation elems
    const size_t WSZ = (size_t)1024 * 1024;           // weight elems
    unsigned short* Qb  = (unsigned short*)d_ws;      // bf16
    unsigned short* Kb  = Qb + SZ;
    unsigned short* Vb  = Kb + SZ;
    unsigned short* Ab  = Vb + SZ;
    unsigned short* WQt = Ab + SZ;
    unsigned short* WKt = WQt + WSZ;
    unsigned short* WVt = WKt + WSZ;
    unsigned short* WOt = WVt + WSZ;                  // total ~75.5 MB

    dim3 blk(256);
    dim3 tg(16, 16);
    hipLaunchKernelGGL(transpose_w, tg, blk, 0, stream, W_Q, WQt);
    hipLaunchKernelGGL(transpose_w, tg, blk, 0, stream, W_K, WKt);
    hipLaunchKernelGGL(transpose_w, tg, blk, 0, stream, W_V, WVt);
    hipLaunchKernelGGL(transpose_w, tg, blk, 0, stream, W_O, WOt);

    dim3 gg(8, 64);   // N/128, M/128
    hipLaunchKernelGGL((gemm2<true, true>), gg, blk, 0, stream,
                       queries, WQt, Qb, 8192, 1024, 1024, 0.125f);   // softmax scale folded
    hipLaunchKernelGGL((gemm2<true, true>), gg, blk, 0, stream,
                       keys, WKt, Kb, 8192, 1024, 1024, 1.0f);
    hipLaunchKernelGGL((gemm2<true, true>), gg, blk, 0, stream,
                       values, WVt, Vb, 8192, 1024, 1024, 1.0f);

    hipLaunchKernelGGL(attn_k, dim3(32, 64), blk, 0, stream, Qb, Kb, Vb, Ab);

    hipLaunchKernelGGL((gemm2<false, false>), gg, blk, 0, stream,
                       Ab, WOt, d_out, 8192, 1024, 1024, 1.0f);
}

// Round 3
// 477.623 us; speedup vs baseline: 2.0568x; 1.2132x over previous
//
#include <hip/hip_runtime.h>
#include <hip/hip_bf16.h>

// MHA fwd: B=4,S=2048,D=1024,H=16,DK=DV=64, causal.
// v3: transposed-score flash attention (in-register softmax), V projected
// directly transposed, all GEMMs dual-global_load_lds bf16 (m97 structure).

typedef __attribute__((ext_vector_type(8))) __bf16 bf16x8;
typedef __attribute__((ext_vector_type(8))) unsigned short ushort8v;
typedef __attribute__((ext_vector_type(4))) unsigned short ushort4v;
typedef __attribute__((ext_vector_type(4))) unsigned uint4v;
typedef __attribute__((ext_vector_type(4))) float float4v;

#define MFMA16(a, b, c) __builtin_amdgcn_mfma_f32_16x16x32_bf16((a), (b), (c), 0, 0, 0)
#define GLDS16(g, l)                                                     \
    __builtin_amdgcn_global_load_lds(                                    \
        (const __attribute__((address_space(1))) void*)(g),              \
        (__attribute__((address_space(3))) void*)(l), 16, 0, 0)

__device__ __forceinline__ unsigned short f2bf(float f) {   // RNE
    union { float f; unsigned u; } v; v.f = f;
    unsigned r = v.u + 0x7fffu + ((v.u >> 16) & 1u);
    return (unsigned short)(r >> 16);
}
__device__ __forceinline__ unsigned pkbf(float a, float b) { // 2xf32 -> 2xbf16
    union { float f; unsigned u; } x, y; x.f = a; y.f = b;
    return __builtin_amdgcn_perm(y.u + 0x8000u, x.u + 0x8000u, 0x07060302u);
}

// ---------------------------------------------------------------------------
// fp32 -> bf16 elementwise, 8 elems/thread
__global__ __launch_bounds__(256) void cvt_bf16(
    const float* __restrict__ X, unsigned short* __restrict__ Y)
{
    size_t i = ((size_t)blockIdx.x * 256 + threadIdx.x) * 8;
    float4v a = *(const float4v*)&X[i];
    float4v b = *(const float4v*)&X[i + 4];
    uint4v o = { pkbf(a.x, a.y), pkbf(a.z, a.w), pkbf(b.x, b.y), pkbf(b.z, b.w) };
    *(uint4v*)&Y[i] = o;
}

// ---------------------------------------------------------------------------
// W [K=1024][N=1024] fp32 -> Wt [N][K] bf16, optional scale
__global__ __launch_bounds__(256) void transpose_w(
    const float* __restrict__ W, unsigned short* __restrict__ Wt, float scale)
{
    __shared__ unsigned short T[64][72];
    const int t = threadIdx.x;
    const int n0 = blockIdx.x * 64, k0 = blockIdx.y * 64;
    for (int i = 0; i < 4; i++) {
        int idx = i * 256 + t, r = idx >> 4, c = (idx & 15) * 4;
        float4v v = *(const float4v*)&W[(size_t)(k0 + r) * 1024 + n0 + c];
        T[c + 0][r] = f2bf(v.x * scale); T[c + 1][r] = f2bf(v.y * scale);
        T[c + 2][r] = f2bf(v.z * scale); T[c + 3][r] = f2bf(v.w * scale);
    }
    __syncthreads();
    for (int i = 0; i < 4; i++) {
        int idx = i * 256 + t, r = idx >> 4, c = (idx & 15) * 4;
        ushort4v o; o.x = T[r][c]; o.y = T[r][c + 1]; o.z = T[r][c + 2]; o.w = T[r][c + 3];
        *(ushort4v*)&Wt[(size_t)(n0 + r) * 1024 + k0 + c] = o;
    }
}

// ---------------------------------------------------------------------------
// C[M,N] = A[M,K] @ Bt[N,K]^T, both bf16 via global_load_lds. 128x128, BK=64.
template <bool OUT_BF16>
__global__ __launch_bounds__(256) void gemm_bb(
    const unsigned short* __restrict__ A, const unsigned short* __restrict__ Bt,
    void* __restrict__ Cp, int M, int N, int K)
{
    __shared__ unsigned short As[128 * 64];
    __shared__ unsigned short Bs[128 * 64];

    const int t = threadIdx.x;
    const int lane = t & 63, w = t >> 6;
    const int lanelo = lane & 15, quad = lane >> 4;
    const int wm = w >> 1, wn = w & 1;
    const int m0 = blockIdx.y * 128, n0 = blockIdx.x * 128;

    float4v acc[4][4];
    for (int i = 0; i < 4; i++)
        for (int j = 0; j < 4; j++) acc[i][j] = (float4v)(0.f);

    for (int k0 = 0; k0 < K; k0 += 64) {
        for (int i = 0; i < 4; i++) {
            int idx = i * 256 + t, row = idx >> 3, ch = idx & 7;
            GLDS16(A + (size_t)(m0 + row) * K + k0 + ch * 8, &As[idx * 8]);
        }
        for (int i = 0; i < 4; i++) {
            int idx = i * 256 + t, row = idx >> 3, ch = idx & 7;
            GLDS16(Bt + (size_t)(n0 + row) * K + k0 + ch * 8, &Bs[idx * 8]);
        }
        __syncthreads();
        for (int ks = 0; ks < 2; ks++) {
            bf16x8 af[4], bfr[4];
            for (int mi = 0; mi < 4; mi++)
                af[mi] = *(const bf16x8*)&As[(wm * 64 + mi * 16 + lanelo) * 64 + ks * 32 + quad * 8];
            for (int ni = 0; ni < 4; ni++)
                bfr[ni] = *(const bf16x8*)&Bs[(wn * 64 + ni * 16 + lanelo) * 64 + ks * 32 + quad * 8];
            for (int mi = 0; mi < 4; mi++)
                for (int ni = 0; ni < 4; ni++)
                    acc[mi][ni] = MFMA16(af[mi], bfr[ni], acc[mi][ni]);
        }
        __syncthreads();
    }

    for (int mi = 0; mi < 4; mi++)
        for (int ni = 0; ni < 4; ni++) {
            int col = n0 + wn * 64 + ni * 16 + lanelo;
            for (int r = 0; r < 4; r++) {
                int row = m0 + wm * 64 + mi * 16 + quad * 4 + r;
                float v = acc[mi][ni][r];
                if constexpr (OUT_BF16)
                    ((unsigned short*)Cp)[(size_t)row * N + col] = f2bf(v);
                else
                    ((float*)Cp)[(size_t)row * N + col] = v;
            }
        }
}

// ---------------------------------------------------------------------------
// Flash causal attention, transposed scores.  Block = 64 Q-rows of one (b,h).
// S^T = K Q^T: lane holds one q-column (q = lanelo), 16 keys in regs ->
// in-register softmax + 2 cross-quad shuffles.  V^T tile via global_load_lds.
// P^T -> LDS (b64 writes) -> B-operand for O^T = V^T P^T.
// ---------------------------------------------------------------------------
__global__ __launch_bounds__(256) void attn_k(
    const unsigned short* __restrict__ Qb, const unsigned short* __restrict__ Kb,
    const unsigned short* __restrict__ Vt, unsigned short* __restrict__ Ob)
{
    __shared__ unsigned short Ks[64 * 64];
    __shared__ unsigned short Vs[64 * 64];
    __shared__ unsigned short Ps[4][16 * 72];

    const int t = threadIdx.x;
    const int lane = t & 63, w = t >> 6;
    const int lanelo = lane & 15, quad = lane >> 4;
    const int qt = gridDim.x - 1 - blockIdx.x;          // heavy blocks first
    const int qb = qt * 64;
    const int bh = blockIdx.y;
    const int b = bh >> 4, h = bh & 15;

    // Q fragments (B-operand: n = q = lanelo, k = quad*8+j)
    const int q = qb + w * 16 + lanelo;
    bf16x8 qf[2];
    {
        const unsigned short* qp = Qb + ((size_t)(b * 2048) + q) * 1024 + h * 64 + quad * 8;
        qf[0] = *(const bf16x8*)(qp);
        qf[1] = *(const bf16x8*)(qp + 32);
    }

    float4v o[4];
    for (int i = 0; i < 4; i++) o[i] = (float4v)(0.f);
    float m_ = -__builtin_inff(), l_ = 0.f;

    const int nkt = qt + 1;
    unsigned short* pw = &Ps[w][0];

    for (int kt = 0; kt < nkt; kt++) {
        // K tile [key][d] and V^T tile [dv][key], both async 16B
        for (int i = 0; i < 2; i++) {
            int idx = i * 256 + t;
            GLDS16(Kb + ((size_t)(b * 2048 + kt * 64 + (idx >> 3))) * 1024 + h * 64 + (idx & 7) * 8,
                   &Ks[idx * 8]);
        }
        for (int i = 0; i < 2; i++) {
            int idx = i * 256 + t;
            GLDS16(Vt + (size_t)(h * 64 + (idx >> 3)) * 8192 + b * 2048 + kt * 64 + (idx & 7) * 8,
                   &Vs[idx * 8]);
        }
        __syncthreads();

        if (kt * 64 <= qb + w * 16 + 15) {              // wave-uniform causal skip
            // S^T tiles: A = K rows (m=key), B = Q rows (n=q)
            float4v sc[4];
            for (int nt = 0; nt < 4; nt++) {
                sc[nt] = (float4v)(0.f);
                for (int c = 0; c < 2; c++) {
                    bf16x8 kf = *(const bf16x8*)&Ks[(nt * 16 + lanelo) * 64 + c * 32 + quad * 8];
                    sc[nt] = MFMA16(kf, qf[c], sc[nt]);
                }
            }
            // lane holds keys {kt*64 + nt*16 + quad*4 + r} for column q
            const int kb0 = kt * 64 + quad * 4;
            float mx = -__builtin_inff();
            for (int nt = 0; nt < 4; nt++)
                for (int r = 0; r < 4; r++) {
                    float s = sc[nt][r];
                    if (kb0 + nt * 16 + r > q) s = -__builtin_inff();
                    sc[nt][r] = s;
                    mx = fmaxf(mx, s);
                }
            mx = fmaxf(mx, __shfl_xor(mx, 16, 64));
            mx = fmaxf(mx, __shfl_xor(mx, 32, 64));
            float mnew = fmaxf(m_, mx);
            float alpha = __expf(m_ - mnew);
            float rs = 0.f;
            for (int nt = 0; nt < 4; nt++)
                for (int r = 0; r < 4; r++) {
                    float e = __expf(sc[nt][r] - mnew);
                    sc[nt][r] = e; rs += e;
                }
            rs += __shfl_xor(rs, 16, 64);
            rs += __shfl_xor(rs, 32, 64);
            l_ = l_ * alpha + rs;
            m_ = mnew;
            for (int vt = 0; vt < 4; vt++)
                for (int r = 0; r < 4; r++) o[vt][r] *= alpha;

            // P^T -> LDS rows [q=lanelo][key_local], b64 writes (r contiguous)
            for (int nt = 0; nt < 4; nt++) {
                ushort4v pv = { f2bf(sc[nt][0]), f2bf(sc[nt][1]),
                                f2bf(sc[nt][2]), f2bf(sc[nt][3]) };
                *(ushort4v*)&pw[lanelo * 72 + nt * 16 + quad * 4] = pv;
            }
            asm volatile("s_waitcnt lgkmcnt(0)" ::: "memory");
            // O^T += V^T P^T : A = V^T (m=dv), B = P (n=q)
            for (int c = 0; c < 2; c++) {
                bf16x8 pf = *(const bf16x8*)&pw[lanelo * 72 + c * 32 + quad * 8];
                for (int vt = 0; vt < 4; vt++) {
                    bf16x8 vf = *(const bf16x8*)&Vs[(vt * 16 + lanelo) * 64 + c * 32 + quad * 8];
                    o[vt] = MFMA16(vf, pf, o[vt]);
                }
            }
        }
        __syncthreads();
    }

    // epilogue: normalize, transpose O^T -> O via per-wave P buffer, 16B stores
    float inv = 1.0f / l_;
    for (int vt = 0; vt < 4; vt++) {
        ushort4v ov = { f2bf(o[vt][0] * inv), f2bf(o[vt][1] * inv),
                        f2bf(o[vt][2] * inv), f2bf(o[vt][3] * inv) };
        *(ushort4v*)&pw[lanelo * 72 + vt * 16 + quad * 4] = ov;
    }
    asm volatile("s_waitcnt lgkmcnt(0)" ::: "memory");
    for (int i = 0; i < 2; i++) {
        int qr = i * 8 + (lane >> 3);
        int dv0 = (lane & 7) * 8;
        ushort8v ov = *(const ushort8v*)&pw[qr * 72 + dv0];
        *(ushort8v*)(Ob + ((size_t)(b * 2048) + qb + w * 16 + qr) * 1024 + h * 64 + dv0) = ov;
    }
}

// ---------------------------------------------------------------------------
extern "C" void kernel_launch(void* const* d_in, const int* in_sizes, int n_in,
                              void* d_out, int out_size, void* d_ws, size_t ws_size,
                              hipStream_t stream) {
    const float* queries = (const float*)d_in[0];
    const float* keys    = (const float*)d_in[1];
    const float* values  = (const float*)d_in[2];
    // d_in[3] = causal mask, handled analytically
    const float* W_Q = (const float*)d_in[4];
    const float* W_K = (const float*)d_in[5];
    const float* W_V = (const float*)d_in[6];
    const float* W_O = (const float*)d_in[7];

    const size_t SZ = (size_t)4 * 2048 * 1024;        // 8.4M elems
    const size_t WSZ = (size_t)1024 * 1024;
    unsigned short* X   = (unsigned short*)d_ws;      // converted activations
    unsigned short* Qb  = X + SZ;
    unsigned short* Kb  = Qb + SZ;
    unsigned short* Vt  = Kb + SZ;                    // [1024][8192]
    unsigned short* Ab  = X;                          // alias (X dead after VT GEMM)
    unsigned short* WQt = Vt + SZ;
    unsigned short* WKt = WQt + WSZ;
    unsigned short* WVt = WKt + WSZ;
    unsigned short* WOt = WVt + WSZ;                  // ~75.2 MB total

    dim3 blk(256), tg(16, 16);
    hipLaunchKernelGGL(transpose_w, tg, blk, 0, stream, W_Q, WQt, 1.0f);
    hipLaunchKernelGGL(transpose_w, tg, blk, 0, stream, W_K, WKt, 0.125f); // fold softmax scale
    hipLaunchKernelGGL(transpose_w, tg, blk, 0, stream, W_V, WVt, 1.0f);
    hipLaunchKernelGGL(transpose_w, tg, blk, 0, stream, W_O, WOt, 1.0f);

    dim3 cg(4096);
    // Q = Xq @ WQ^T
    hipLaunchKernelGGL(cvt_bf16, cg, blk, 0, stream, queries, X);
    hipLaunchKernelGGL((gemm_bb<true>), dim3(8, 64), blk, 0, stream, X, WQt, Qb, 8192, 1024, 1024);
    // K = Xk @ WK^T (pre-scaled)
    hipLaunchKernelGGL(cvt_bf16, cg, blk, 0, stream, keys, X);
    hipLaunchKernelGGL((gemm_bb<true>), dim3(8, 64), blk, 0, stream, X, WKt, Kb, 8192, 1024, 1024);
    // V^T = WV^T @ Xv^T  (M=1024 rows of W, N=8192 seq)
    hipLaunchKernelGGL(cvt_bf16, cg, blk, 0, stream, values, X);
    hipLaunchKernelGGL((gemm_bb<true>), dim3(64, 8), blk, 0, stream, WVt, X, Vt, 1024, 8192, 1024);

    hipLaunchKernelGGL(attn_k, dim3(32, 64), blk, 0, stream, Qb, Kb, Vt, Ab);

    hipLaunchKernelGGL((gemm_bb<false>), dim3(8, 64), blk, 0, stream, Ab, WOt, d_out, 8192, 1024, 1024);
}